// Round 10
// baseline (131.206 us; speedup 1.0000x reference)
//
#include <hip/hip_runtime.h>
#include <hip/hip_bf16.h>

typedef short short8 __attribute__((ext_vector_type(8)));
typedef float f32x4 __attribute__((ext_vector_type(4)));

__device__ __forceinline__ unsigned short f2bf(float f) {
  union { float f; unsigned u; } v; v.f = f;
  unsigned u = v.u;
  unsigned r = (u + 0x7FFFu + ((u >> 16) & 1u)) >> 16;  // RNE
  return (unsigned short)r;
}

// ---------------------------------------------------------------------------
// Precompute W' = W H (H = orthonormal Haar analysis matrix), i.e.
// out = W coeffs(x) = (W H) x. Closed form (no cascade, no barriers):
//   W'[e,k] = W[e,0]*2^-4 + sum_{l=1..8} (+/-) 2^{-l/2} * W[e, 2^{8-l} + (k>>l)]
//   sign = -1 if bit (l-1) of k else +1.
// Packed bf16 in MFMA fragment layout:
//   flat index = ((nblk*8 + kk)*64 + lane)*8 + j
//   where e = nblk*16 + (lane&15), k = kk*32 + (lane>>4)*8 + j
// ---------------------------------------------------------------------------
__global__ void haar_pack(const float* __restrict__ W, unsigned short* __restrict__ Wp) {
  const int e = blockIdx.x;       // 256
  const int k = threadIdx.x;      // 256
  const float* row = W + e * 256;
  const float wgt[9] = {0.f,
    0.70710678118654752f, 0.5f, 0.35355339059327376f, 0.25f,
    0.17677669529663688f, 0.125f, 0.08838834764831844f, 0.0625f};
  float acc = row[0] * 0.0625f;   // cA_8 tap, weight 2^-4
#pragma unroll
  for (int l = 1; l <= 8; ++l) {
    float g = wgt[l];
    float s = ((k >> (l - 1)) & 1) ? -g : g;
    acc += row[(1 << (8 - l)) + (k >> l)] * s;
  }
  const int nblk = e >> 4, lr = e & 15;
  const int kk = k >> 5, win = k & 31, lhi = win >> 3, j = win & 7;
  const int lane = lhi * 16 + lr;
  Wp[(((nblk * 8 + kk) * 64 + lane) << 3) + j] = f2bf(acc);
}

// ---------------------------------------------------------------------------
// R10: barrier-free, LDS-free streaming GEMM.  out[m,e] = x[m,:].W'[e,:] + b[e]
// - mfma(W'frag, xfrag): x is the B-operand -> lane (lr,lhi) needs
//   x[row=base+lr, k = kk*32 + lhi*8 .. +7] = 32 contiguous bytes -> DIRECT
//   global float4 pair loads; wave covers 16 rows x 128 B dense. No LDS,
//   no __syncthreads anywhere; every wave streams independently.
// - 8 waves/block (512 thr), wave = 32-e slice (wn*32): Bf[8][2] = 64 VGPR,
//   pinned resident (total wave state ~190 VGPR < 256 cap at 2 waves/SIMD).
//   Residency keeps the vmcnt FIFO clean: in-loop VMEM = P-prefetch (next
//   tile, 8 loads) + Q (this tile kk4-7, 8 loads) + 2 stores; mfma03 waits
//   only the oldest 8 (P arrived long ago), mfma47 waits vmcnt(8) leaving
//   the prefetch in flight. Stores never drained in-loop.
// - D-layout (swapped): col=lane&15 = m-row, row=(lane>>4)*4+reg = e ->
//   one dwordx4 store per mfma pair; acc initialized to bias.
// - grid 512 x 512 thr, NT=16 tiles of 16 rows per block.
// ---------------------------------------------------------------------------
#define NT 16

__global__ __launch_bounds__(512, 1) void wemb_gemm(
    const float* __restrict__ x, const unsigned short* __restrict__ Wp,
    const float* __restrict__ bias, float* __restrict__ out) {
  const int tid = threadIdx.x;
  const int wn = tid >> 6;              // 0..7 -> e-slice wn*32
  const int lane = tid & 63;
  const int lr = lane & 15, lhi = lane >> 4;

  // ---- W' fragments -> registers, loaded once, pinned resident ----
  short8 Bf[8][2];   // [kk][n]
#pragma unroll
  for (int kk = 0; kk < 8; ++kk)
#pragma unroll
    for (int n = 0; n < 2; ++n)
      Bf[kk][n] = *(const short8*)(Wp + ((((wn * 2 + n) * 8 + kk) * 64 + lane) << 3));
#pragma unroll
  for (int kk = 0; kk < 8; ++kk)
#pragma unroll
    for (int n = 0; n < 2; ++n)
      asm volatile("" : "+v"(Bf[kk][n]));

  f32x4 bias4[2];
#pragma unroll
  for (int n = 0; n < 2; ++n)
    bias4[n] = *(const f32x4*)(bias + wn * 32 + n * 16 + lhi * 4);

  const long row0 = (long)blockIdx.x * (16 * NT) + lr;   // this lane's row
  const float* xbase = x + row0 * 256 + lhi * 8;         // + k-group offset

  float4 PA[8], PB[8], Q[8];

  // ---- prologue: P-half (kk 0..3) of tile 0 ----
#pragma unroll
  for (int i = 0; i < 8; ++i)
    PA[i] = *(const float4*)(xbase + (i >> 1) * 32 + (i & 1) * 4);

#define CVT8(FR, LO, HI) { \
    union { short8 s; unsigned short h[8]; } u_;                              \
    u_.h[0] = __bfloat16_as_ushort(__float2bfloat16((LO).x));                 \
    u_.h[1] = __bfloat16_as_ushort(__float2bfloat16((LO).y));                 \
    u_.h[2] = __bfloat16_as_ushort(__float2bfloat16((LO).z));                 \
    u_.h[3] = __bfloat16_as_ushort(__float2bfloat16((LO).w));                 \
    u_.h[4] = __bfloat16_as_ushort(__float2bfloat16((HI).x));                 \
    u_.h[5] = __bfloat16_as_ushort(__float2bfloat16((HI).y));                 \
    u_.h[6] = __bfloat16_as_ushort(__float2bfloat16((HI).z));                 \
    u_.h[7] = __bfloat16_as_ushort(__float2bfloat16((HI).w));                 \
    FR = u_.s;                                                                \
  }

#define STEP(T, PC, PN)                                                       \
  {                                                                           \
    const float* xr = xbase + (long)(T) * (16 * 256);                         \
    _Pragma("unroll")                                                         \
    for (int i = 0; i < 8; ++i)   /* Q: kk 4..7 of this tile */               \
      Q[i] = *(const float4*)(xr + 128 + (i >> 1) * 32 + (i & 1) * 4);        \
    if ((T) + 1 < NT) {           /* P: kk 0..3 of NEXT tile */               \
      _Pragma("unroll")                                                       \
      for (int i = 0; i < 8; ++i)                                             \
        PN[i] = *(const float4*)(xr + 16 * 256 + (i >> 1) * 32 + (i & 1) * 4);\
    }                                                                         \
    f32x4 acc[2];                                                             \
    acc[0] = bias4[0]; acc[1] = bias4[1];                                     \
    _Pragma("unroll")                                                         \
    for (int kk = 0; kk < 4; ++kk) {                                          \
      short8 fr; CVT8(fr, PC[2 * kk], PC[2 * kk + 1]);                        \
      _Pragma("unroll")                                                       \
      for (int n = 0; n < 2; ++n)                                             \
        acc[n] = __builtin_amdgcn_mfma_f32_16x16x32_bf16(Bf[kk][n], fr,       \
                                                         acc[n], 0, 0, 0);    \
    }                                                                         \
    _Pragma("unroll")                                                         \
    for (int kk = 4; kk < 8; ++kk) {                                          \
      short8 fr; CVT8(fr, Q[2 * (kk - 4)], Q[2 * (kk - 4) + 1]);              \
      _Pragma("unroll")                                                       \
      for (int n = 0; n < 2; ++n)                                             \
        acc[n] = __builtin_amdgcn_mfma_f32_16x16x32_bf16(Bf[kk][n], fr,       \
                                                         acc[n], 0, 0, 0);    \
    }                                                                         \
    float* orow = out + (row0 + (T) * 16) * 256 + wn * 32 + lhi * 4;          \
    *(f32x4*)(orow) = acc[0];                                                 \
    *(f32x4*)(orow + 16) = acc[1];                                            \
  }

#pragma unroll 1
  for (int tp = 0; tp < NT / 2; ++tp) {
    STEP(tp * 2,     PA, PB);
    STEP(tp * 2 + 1, PB, PA);
  }
#undef STEP
#undef CVT8
}

extern "C" void kernel_launch(void* const* d_in, const int* in_sizes, int n_in,
                              void* d_out, int out_size, void* d_ws, size_t ws_size,
                              hipStream_t stream) {
  const float* x = (const float*)d_in[0];     // (16, 8192, 256) fp32
  const float* W = (const float*)d_in[1];     // (256, 256) fp32
  const float* b = (const float*)d_in[2];     // (256,) fp32
  float* out = (float*)d_out;                 // (16, 8192, 256) fp32
  unsigned short* Wp = (unsigned short*)d_ws; // 256*256 bf16 = 128 KB

  haar_pack<<<256, 256, 0, stream>>>(W, Wp);

  const int grid = (out_size / 256) / (16 * NT);  // 131072 / 256 = 512
  wemb_gemm<<<grid, 512, 0, stream>>>(x, Wp, b, out);
}

// Round 11
// 59.545 us; speedup vs baseline: 2.2035x; 2.2035x over previous
//
#include <hip/hip_runtime.h>
#include <hip/hip_bf16.h>

typedef short short8 __attribute__((ext_vector_type(8)));
typedef float f32x4 __attribute__((ext_vector_type(4)));

__device__ __forceinline__ unsigned short f2bf(float f) {
  union { float f; unsigned u; } v; v.f = f;
  unsigned u = v.u;
  unsigned r = (u + 0x7FFFu + ((u >> 16) & 1u)) >> 16;  // RNE
  return (unsigned short)r;
}

// ---------------------------------------------------------------------------
// Precompute W' = W H (orthonormal Haar), closed form, fragment-packed bf16.
//   W'[e,k] = W[e,0]*2^-4 + sum_{l=1..8} (+/-) 2^{-l/2} * W[e, 2^{8-l} + (k>>l)]
//   flat index = ((nblk*8 + kk)*64 + lane)*8 + j ; e = nblk*16+(lane&15),
//   k = kk*32 + (lane>>4)*8 + j
// ---------------------------------------------------------------------------
__global__ void haar_pack(const float* __restrict__ W, unsigned short* __restrict__ Wp) {
  const int e = blockIdx.x;       // 256
  const int k = threadIdx.x;      // 256
  const float* row = W + e * 256;
  const float wgt[9] = {0.f,
    0.70710678118654752f, 0.5f, 0.35355339059327376f, 0.25f,
    0.17677669529663688f, 0.125f, 0.08838834764831844f, 0.0625f};
  float acc = row[0] * 0.0625f;
#pragma unroll
  for (int l = 1; l <= 8; ++l) {
    float g = wgt[l];
    float s = ((k >> (l - 1)) & 1) ? -g : g;
    acc += row[(1 << (8 - l)) + (k >> l)] * s;
  }
  const int nblk = e >> 4, lr = e & 15;
  const int kk = k >> 5, win = k & 31, lhi = win >> 3, j = win & 7;
  const int lane = lhi * 16 + lr;
  Wp[(((nblk * 8 + kk) * 64 + lane) << 3) + j] = f2bf(acc);
}

// ---------------------------------------------------------------------------
// R11: async-DMA streaming GEMM.  out[m,e] = x[m,:].W'[e,:] + b[e]
// - Staging via __builtin_amdgcn_global_load_lds (16B/lane): NO VGPR round
//   trip, NO cvt-before-write, NO ds_write. fp32 tiles, 3-slot LDS ring
//   (3 x 32 KB); bf16 convert on the read side.
// - Counted vmcnt (12 steady / 8 edges / 4 prologue) + raw s_barrier: DMA
//   loads stay in flight ACROSS barriers (T3/T4); stores never drained.
//   Counts are hoist-proofed by sched_barrier(0) fences and remain safe if
//   the compiler adds VMEM ops (extra ops only make vmcnt(N) stricter).
// - Source-side swizzle (LDS linear, m173): 16B-unit u at row goes to LDS
//   unit u ^ FSWZ(row); read applies the same XOR -> fragment ds_read_b128
//   hits the structural-minimum bank distribution (8 lanes/4-bank group).
// - 8 waves (2wm x 4wn), wave tile 16m x 64e; NT=16 tiles of 32 rows;
//   grid 256. mfma(W'frag, xfrag) -> transposed D: one dwordx4 store per
//   n-frag (4/wave/tile), acc initialized from bias.
// ---------------------------------------------------------------------------
#define NT 16

#define FSWZ(ROW) ((((ROW) & 3) << 1) | (((ROW) >> 2) & 1) | ((((ROW) >> 3) & 1) << 3))

__device__ __forceinline__ void gload16(const float* src, void* lds_dst) {
  __builtin_amdgcn_global_load_lds(
      (const __attribute__((address_space(1))) void*)src,
      (__attribute__((address_space(3))) void*)lds_dst, 16, 0, 0);
}

#define WAIT_VM(N) asm volatile("s_waitcnt vmcnt(" #N ")" ::: "memory")
#define BAR() do { __builtin_amdgcn_s_barrier(); \
                   __builtin_amdgcn_sched_barrier(0); } while (0)

__global__ __launch_bounds__(512, 1) void wemb_gemm(
    const float* __restrict__ x, const unsigned short* __restrict__ Wp,
    const float* __restrict__ bias, float* __restrict__ out) {
  __shared__ char lds[3 * 32768];
  const int tid = threadIdx.x;
  const int w = tid >> 6, lane = tid & 63;
  const int wm = w >> 2, wn = w & 3;      // 2 x 4 wave grid
  const int lr = lane & 15, lhi = lane >> 4;
  const long blockRow = (long)blockIdx.x * (32 * NT);

  // ---- W' fragments (A-operand); source proven perf-neutral R4/R6/R7 ----
  short8 Bf[8][4];   // [kk][n]
#pragma unroll
  for (int kk = 0; kk < 8; ++kk)
#pragma unroll
    for (int n = 0; n < 4; ++n)
      Bf[kk][n] = *(const short8*)(Wp + ((((wn * 4 + n) * 8 + kk) * 64 + lane) << 3));

  f32x4 bias4[4];    // e = wn*64 + n*16 + lhi*4 + r
#pragma unroll
  for (int n = 0; n < 4; ++n)
    bias4[n] = *(const f32x4*)(bias + wn * 64 + n * 16 + lhi * 4);

  // ---- staging: wave w stages rows w*4..w*4+3 of each tile (1KB/row DMA),
  //      source address lane-swizzled so linear LDS holds swizzled layout ----
#define STAGE(T)                                                              \
  {                                                                           \
    const float* xs = x + (blockRow + (long)(T) * 32) * 256;                  \
    char* slot = lds + ((T) % 3) * 32768;                                     \
    _Pragma("unroll")                                                         \
    for (int r = 0; r < 4; ++r) {                                             \
      const int row = w * 4 + r;                                              \
      const int fr = FSWZ(row);                                               \
      gload16(xs + row * 256 + ((lane ^ fr) << 2),                            \
              slot + row * 1024 + lane * 16);                                 \
    }                                                                         \
  }

  // ---- body: compute tile T from ring, stage T+2, store T ----
#define BODY(T)                                                               \
  {                                                                           \
    if ((T) + 2 < NT) STAGE((T) + 2);                                         \
    __builtin_amdgcn_sched_barrier(0);                                        \
    const char* slot = lds + ((T) % 3) * 32768;                               \
    const int arow = wm * 16 + lr;                                            \
    const int fr = FSWZ(arow);                                                \
    f32x4 acc[4];                                                             \
    _Pragma("unroll")                                                         \
    for (int n = 0; n < 4; ++n) acc[n] = bias4[n];                            \
    _Pragma("unroll")                                                         \
    for (int kk = 0; kk < 8; ++kk) {                                          \
      const int u0 = kk * 8 + lhi * 2;                                        \
      f32x4 lo = *(const f32x4*)(slot + arow * 1024 + ((u0 ^ fr) << 4));      \
      f32x4 hi = *(const f32x4*)(slot + arow * 1024 + (((u0 + 1) ^ fr) << 4));\
      union { short8 s; unsigned short h[8]; } u_;                            \
      u_.h[0] = __bfloat16_as_ushort(__float2bfloat16(lo.x));                 \
      u_.h[1] = __bfloat16_as_ushort(__float2bfloat16(lo.y));                 \
      u_.h[2] = __bfloat16_as_ushort(__float2bfloat16(lo.z));                 \
      u_.h[3] = __bfloat16_as_ushort(__float2bfloat16(lo.w));                 \
      u_.h[4] = __bfloat16_as_ushort(__float2bfloat16(hi.x));                 \
      u_.h[5] = __bfloat16_as_ushort(__float2bfloat16(hi.y));                 \
      u_.h[6] = __bfloat16_as_ushort(__float2bfloat16(hi.z));                 \
      u_.h[7] = __bfloat16_as_ushort(__float2bfloat16(hi.w));                 \
      _Pragma("unroll")                                                       \
      for (int n = 0; n < 4; ++n)                                             \
        acc[n] = __builtin_amdgcn_mfma_f32_16x16x32_bf16(Bf[kk][n], u_.s,     \
                                                         acc[n], 0, 0, 0);    \
    }                                                                         \
    float* orow = out + (blockRow + (T) * 32 + wm * 16 + lr) * 256            \
                      + wn * 64 + lhi * 4;                                    \
    _Pragma("unroll")                                                         \
    for (int n = 0; n < 4; ++n) *(f32x4*)(orow + n * 16) = acc[n];            \
  }

  // ---- prologue: stage tiles 0,1; wait for 0 ----
  STAGE(0);
  __builtin_amdgcn_sched_barrier(0);
  STAGE(1);
  __builtin_amdgcn_sched_barrier(0);
  WAIT_VM(4);          // stage(0) done (stage(1)'s 4 ops may be in flight)
  BAR();

  // Steady-state FIFO between stage(t) [body t-2] and wait(t):
  //   stores(t-2):4 + stage(t+1):4 + stores(t-1):4 = 12  -> vmcnt(12)
  // Edges: wait(1): stage(2):4+stores(0):4=8; wait(15): stores(13):4+stores(14):4=8.
#pragma unroll 1
  for (int tp = 0; tp < NT / 2; ++tp) {
    const int t0 = tp * 2;
    BODY(t0);
    if (tp == 0 || tp == NT / 2 - 1) { WAIT_VM(8); } else { WAIT_VM(12); }
    BAR();
    BODY(t0 + 1);
    if (tp < NT / 2 - 1) { WAIT_VM(12); BAR(); }
  }
#undef BODY
#undef STAGE
}

extern "C" void kernel_launch(void* const* d_in, const int* in_sizes, int n_in,
                              void* d_out, int out_size, void* d_ws, size_t ws_size,
                              hipStream_t stream) {
  const float* x = (const float*)d_in[0];     // (16, 8192, 256) fp32
  const float* W = (const float*)d_in[1];     // (256, 256) fp32
  const float* b = (const float*)d_in[2];     // (256,) fp32
  float* out = (float*)d_out;                 // (16, 8192, 256) fp32
  unsigned short* Wp = (unsigned short*)d_ws; // 256*256 bf16 = 128 KB

  haar_pack<<<256, 256, 0, stream>>>(W, Wp);

  const int grid = (out_size / 256) / (32 * NT);  // 131072 / 512 = 256
  wemb_gemm<<<grid, 512, 0, stream>>>(x, Wp, b, out);
}